// Round 8
// baseline (261.523 us; speedup 1.0000x reference)
//
#include <hip/hip_runtime.h>
#include <math.h>

typedef __bf16 bf16x8 __attribute__((ext_vector_type(8)));
typedef __bf16 bf16x4 __attribute__((ext_vector_type(4)));
typedef short shortx4 __attribute__((ext_vector_type(4)));
typedef float floatx4 __attribute__((ext_vector_type(4)));

#define Tc 2048
#define Cdim 1024
#define Hc 16
#define Dc 64
#define Mrows 8192

__device__ __forceinline__ float bf2f(ushort u) {
  union { float f; unsigned int i; } v; v.i = ((unsigned int)u) << 16; return v.f;
}
__device__ __forceinline__ ushort f2bf(float f) {
  union { float f; unsigned int i; } v; v.f = f;
  unsigned int r = (v.i + 0x7FFFu + ((v.i >> 16) & 1u)) >> 16;
  return (ushort)r;
}
__device__ __forceinline__ float exp2_fast(float x) {
#if __has_builtin(__builtin_amdgcn_exp2f)
  return __builtin_amdgcn_exp2f(x);
#else
  return exp2f(x);
#endif
}

// ---- 16x16x16 bf16 MFMA with compile-safe fallbacks (round-4 verified) ----
#if __has_builtin(__builtin_amdgcn_mfma_f32_16x16x16_bf16)
__device__ __forceinline__ floatx4 mfma16(bf16x4 a, bf16x4 b, floatx4 c) {
  return __builtin_amdgcn_mfma_f32_16x16x16_bf16(a, b, c, 0, 0, 0);
}
#elif __has_builtin(__builtin_amdgcn_mfma_f32_16x16x16bf16_1k)
__device__ __forceinline__ floatx4 mfma16(bf16x4 a, bf16x4 b, floatx4 c) {
  union { bf16x4 bv; shortx4 sv; } ua, ub;
  ua.bv = a; ub.bv = b;
  return __builtin_amdgcn_mfma_f32_16x16x16bf16_1k(ua.sv, ub.sv, c, 0, 0, 0);
}
#else
__device__ __forceinline__ floatx4 mfma16(bf16x4 a, bf16x4 b, floatx4 c) {
  floatx4 d;
  asm("v_mfma_f32_16x16x16_bf16 %0, %1, %2, %3" : "=v"(d) : "v"(a), "v"(b), "v"(c));
  return d;
}
#endif

#if __has_builtin(__builtin_amdgcn_global_load_lds)
#define HAVE_GLL 1
__device__ __forceinline__ void async_load16(const ushort* g, ushort* l) {
  __builtin_amdgcn_global_load_lds((const __attribute__((address_space(1))) void*)g,
                                   (__attribute__((address_space(3))) void*)l, 16, 0, 0);
}
#else
#define HAVE_GLL 0
#endif

// ---------- fused preprocess: sniff + convert x + transpose W's + biases ----
// One dispatch replaces 6 (sniff, convert x, convert bqkv, convert bout,
// transpose Wqkv, transpose Wout): each launch boundary costs ~8-10 us and
// the E2E accounting showed ~85 us of gaps across 9 serial launches.
// Every block computes the dtype sniff locally from x[0..1023] words
// (deterministic, 4 KB, L2-hot after first block) -> no flag dependency.
// Block ranges: [0,8192) x-convert | [8192,11264) Wqkv 32x32 transpose tiles
// | [11264,12288) Wout tiles | [12288,12291) bqkv | 12291 bout.
// Block 0 also writes ws flag for gemm_out.
__global__ __launch_bounds__(256) void preprocess(
    const void* __restrict__ x, const void* __restrict__ Wqkv,
    const void* __restrict__ bqkv, const void* __restrict__ Wout,
    const void* __restrict__ bout,
    ushort* __restrict__ xb, ushort* __restrict__ wqt, ushort* __restrict__ bqb,
    ushort* __restrict__ wot, ushort* __restrict__ bob, int* __restrict__ flag) {
  const int tid = threadIdx.x;
  __shared__ int cnt;
  __shared__ float tile[32][33];
  if (tid == 0) cnt = 0;
  __syncthreads();
  {
    const unsigned int* xw = (const unsigned int*)x;
    int local = 0;
    #pragma unroll
    for (int i = 0; i < 4; ++i) {
      unsigned int e = (xw[tid + i * 256] >> 7) & 0xFFu;
      if (e >= 100u && e <= 140u) local++;
    }
    atomicAdd(&cnt, local);
  }
  __syncthreads();
  const bool isbf = (cnt >= 614);
  const int bid = blockIdx.x;
  if (bid == 0 && tid == 0) *flag = isbf ? 1 : 0;

  if (bid < 8192) {                     // ---- convert x (4 elems/thread) ----
    const size_t i = (size_t)bid * 256 + tid;
    if (isbf) {
      ((ushort4*)xb)[i] = ((const ushort4*)x)[i];
    } else {
      float4 f = ((const float4*)x)[i];
      ushort4 y;
      y.x = f2bf(f.x); y.y = f2bf(f.y); y.z = f2bf(f.z); y.w = f2bf(f.w);
      ((ushort4*)xb)[i] = y;
    }
    return;
  }
  int t = bid - 8192;
  const int tx = tid & 31, ty = tid >> 5;
  if (t < 3072) {                       // ---- Wqkv^T: [1024][3072]->[3072][1024]
    const int bx = t % 96, by = t / 96;
    #pragma unroll
    for (int i = ty; i < 32; i += 8) {
      const int r = by * 32 + i, c = bx * 32 + tx;
      tile[i][tx] = isbf ? bf2f(((const ushort*)Wqkv)[(size_t)r * 3072 + c])
                         : ((const float*)Wqkv)[(size_t)r * 3072 + c];
    }
    __syncthreads();
    #pragma unroll
    for (int i = ty; i < 32; i += 8) {
      const int cc = bx * 32 + i, rr = by * 32 + tx;
      wqt[(size_t)cc * 1024 + rr] = f2bf(tile[tx][i]);
    }
    return;
  }
  t -= 3072;
  if (t < 1024) {                       // ---- Wout^T: [1024][1024]->[1024][1024]
    const int bx = t & 31, by = t >> 5;
    #pragma unroll
    for (int i = ty; i < 32; i += 8) {
      const int r = by * 32 + i, c = bx * 32 + tx;
      tile[i][tx] = isbf ? bf2f(((const ushort*)Wout)[(size_t)r * 1024 + c])
                         : ((const float*)Wout)[(size_t)r * 1024 + c];
    }
    __syncthreads();
    #pragma unroll
    for (int i = ty; i < 32; i += 8) {
      const int cc = bx * 32 + i, rr = by * 32 + tx;
      wot[(size_t)cc * 1024 + rr] = f2bf(tile[tx][i]);
    }
    return;
  }
  t -= 1024;
  if (t < 3) {                          // ---- bqkv (3 blocks x 1024 elems) ----
    const int i = t * 256 + tid;
    if (isbf) {
      ((ushort4*)bqb)[i] = ((const ushort4*)bqkv)[i];
    } else {
      float4 f = ((const float4*)bqkv)[i];
      ushort4 y;
      y.x = f2bf(f.x); y.y = f2bf(f.y); y.z = f2bf(f.z); y.w = f2bf(f.w);
      ((ushort4*)bqb)[i] = y;
    }
    return;
  }
  {                                     // ---- bout (1 block x 1024 elems) ----
    const int i = tid;
    if (isbf) {
      ((ushort4*)bob)[i] = ((const ushort4*)bout)[i];
    } else {
      float4 f = ((const float4*)bout)[i];
      ushort4 y;
      y.x = f2bf(f.x); y.y = f2bf(f.y); y.z = f2bf(f.z); y.w = f2bf(f.w);
      ((ushort4*)bob)[i] = y;
    }
  }
}

// ===== 256x128 GEMM core: counted-vmcnt pipelined dbuf (BK=64, dist-2) =====
// (round-6 verified; unchanged this round)
#if HAVE_GLL

#define GEMM_CORE(A_, Bt_, acc_)                                               \
  __shared__ __align__(16) ushort As[2][256 * 64];                             \
  __shared__ __align__(16) ushort Bs[2][128 * 64];                             \
  const int tid = threadIdx.x;                                                 \
  const int wave = tid >> 6, lane = tid & 63;                                  \
  const int col = lane & 15, quad = lane >> 4;                                 \
  const int wm = wave >> 1, wn = wave & 1;                                     \
  const int m0 = blockIdx.y * 256, n0 = blockIdx.x * 128;                      \
  const int rl0 = tid >> 3, gsw = (tid & 7) ^ (rl0 & 7);                       \
  floatx4 acc_[4][4];                                                          \
  _Pragma("unroll") for (int i = 0; i < 4; ++i)                                \
    _Pragma("unroll") for (int j = 0; j < 4; ++j)                              \
      acc_[i][j] = (floatx4){0.f, 0.f, 0.f, 0.f};                              \
  auto stage_ = [&](int u) {                                                   \
    const int bb = u & 1;                                                      \
    _Pragma("unroll") for (int h = 0; h < 2; ++h)                              \
      _Pragma("unroll") for (int i = 0; i < 2; ++i) {                          \
        const int rl = i * 64 + rl0;                                           \
        async_load16(A_ + (size_t)(m0 + h * 128 + rl) * 1024 + u * 64 + gsw * 8, \
                     &As[bb][(h * 1024 + i * 512 + wave * 64) * 8]);           \
      }                                                                        \
    _Pragma("unroll") for (int i = 0; i < 2; ++i) {                            \
      const int rl = i * 64 + rl0;                                             \
      async_load16(Bt_ + (size_t)(n0 + rl) * 1024 + u * 64 + gsw * 8,          \
                   &Bs[bb][(i * 512 + wave * 64) * 8]);                        \
    }                                                                          \
  };                                                                           \
  stage_(0);                                                                   \
  stage_(1);                                                                   \
  asm volatile("s_waitcnt vmcnt(6)" ::: "memory");                             \
  __builtin_amdgcn_sched_barrier(0);                                           \
  __builtin_amdgcn_s_barrier();                                                \
  for (int t = 0; t < 16; ++t) {                                               \
    const ushort* Ab = As[t & 1];                                              \
    const ushort* Bb = Bs[t & 1];                                              \
    bf16x8 af[2][4], bfv[2][4];                                                \
    _Pragma("unroll") for (int ks = 0; ks < 2; ++ks) {                         \
      _Pragma("unroll") for (int mi = 0; mi < 4; ++mi) {                       \
        const int rr = wm * 64 + mi * 16 + col;                                \
        const int gg = (ks * 4 + quad) ^ (rr & 7);                             \
        af[ks][mi] = *(const bf16x8*)(Ab + rr * 64 + gg * 8);                  \
      }                                                                        \
      _Pragma("unroll") for (int ni = 0; ni < 4; ++ni) {                       \
        const int rr = wn * 64 + ni * 16 + col;                                \
        const int gg = (ks * 4 + quad) ^ (rr & 7);                             \
        bfv[ks][ni] = *(const bf16x8*)(Bb + rr * 64 + gg * 8);                 \
      }                                                                        \
    }                                                                          \
    asm volatile("s_waitcnt lgkmcnt(0)" ::: "memory");                         \
    __builtin_amdgcn_sched_barrier(0);                                         \
    __builtin_amdgcn_s_barrier();                                              \
    if (t + 2 < 16) stage_(t + 2);                                             \
    __builtin_amdgcn_s_setprio(1);                                             \
    _Pragma("unroll") for (int mi = 0; mi < 4; ++mi)                           \
      _Pragma("unroll") for (int ni = 0; ni < 4; ++ni) {                       \
        acc_[mi][ni] = __builtin_amdgcn_mfma_f32_16x16x32_bf16(                \
            af[0][mi], bfv[0][ni], acc_[mi][ni], 0, 0, 0);                     \
        acc_[mi][ni] = __builtin_amdgcn_mfma_f32_16x16x32_bf16(                \
            af[1][mi], bfv[1][ni], acc_[mi][ni], 0, 0, 0);                     \
      }                                                                        \
    __builtin_amdgcn_s_setprio(0);                                             \
    if (t + 2 < 16) { asm volatile("s_waitcnt vmcnt(6)" ::: "memory"); }       \
    else            { asm volatile("s_waitcnt vmcnt(0)" ::: "memory"); }       \
    __builtin_amdgcn_sched_barrier(0);                                         \
    __builtin_amdgcn_s_barrier();                                              \
  }

#else  // !HAVE_GLL: synchronous dbuf fallback, same geometry (compile safety)

#define GEMM_CORE(A_, Bt_, acc_)                                               \
  __shared__ __align__(16) ushort As[2][256 * 64];                             \
  __shared__ __align__(16) ushort Bs[2][128 * 64];                             \
  const int tid = threadIdx.x;                                                 \
  const int wave = tid >> 6, lane = tid & 63;                                  \
  const int col = lane & 15, quad = lane >> 4;                                 \
  const int wm = wave >> 1, wn = wave & 1;                                     \
  const int m0 = blockIdx.y * 256, n0 = blockIdx.x * 128;                      \
  const int rl0 = tid >> 3, gsw = (tid & 7) ^ (rl0 & 7);                       \
  floatx4 acc_[4][4];                                                          \
  _Pragma("unroll") for (int i = 0; i < 4; ++i)                                \
    _Pragma("unroll") for (int j = 0; j < 4; ++j)                              \
      acc_[i][j] = (floatx4){0.f, 0.f, 0.f, 0.f};                              \
  auto stage_ = [&](int u) {                                                   \
    const int bb = u & 1;                                                      \
    _Pragma("unroll") for (int h = 0; h < 2; ++h)                              \
      _Pragma("unroll") for (int i = 0; i < 2; ++i) {                          \
        const int rl = i * 64 + rl0;                                           \
        *(uint4*)&As[bb][(h * 1024 + i * 512 + wave * 64 + lane) * 8] =        \
            *(const uint4*)(A_ + (size_t)(m0 + h * 128 + rl) * 1024 + u * 64 + gsw * 8); \
      }                                                                        \
    _Pragma("unroll") for (int i = 0; i < 2; ++i) {                            \
      const int rl = i * 64 + rl0;                                             \
      *(uint4*)&Bs[bb][(i * 512 + wave * 64 + lane) * 8] =                     \
          *(const uint4*)(Bt_ + (size_t)(n0 + rl) * 1024 + u * 64 + gsw * 8);  \
    }                                                                          \
  };                                                                           \
  stage_(0);                                                                   \
  __syncthreads();                                                             \
  for (int t = 0; t < 16; ++t) {                                               \
    if (t + 1 < 16) stage_(t + 1);                                             \
    const ushort* Ab = As[t & 1];                                              \
    const ushort* Bb = Bs[t & 1];                                              \
    _Pragma("unroll") for (int ks = 0; ks < 2; ++ks) {                         \
      bf16x8 af[4], bfv[4];                                                    \
      _Pragma("unroll") for (int mi = 0; mi < 4; ++mi) {                       \
        const int rr = wm * 64 + mi * 16 + col;                                \
        const int gg = (ks * 4 + quad) ^ (rr & 7);                             \
        af[mi] = *(const bf16x8*)(Ab + rr * 64 + gg * 8);                      \
      }                                                                        \
      _Pragma("unroll") for (int ni = 0; ni < 4; ++ni) {                       \
        const int rr = wn * 64 + ni * 16 + col;                                \
        const int gg = (ks * 4 + quad) ^ (rr & 7);                             \
        bfv[ni] = *(const bf16x8*)(Bb + rr * 64 + gg * 8);                     \
      }                                                                        \
      _Pragma("unroll") for (int mi = 0; mi < 4; ++mi)                         \
        _Pragma("unroll") for (int ni = 0; ni < 4; ++ni)                       \
          acc_[mi][ni] = __builtin_amdgcn_mfma_f32_16x16x32_bf16(              \
              af[mi], bfv[ni], acc_[mi][ni], 0, 0, 0);                         \
    }                                                                          \
    __syncthreads();                                                           \
  }

#endif  // HAVE_GLL

// ---------- GEMM 1: qkv = x @ W_qkv + b, scatter into Q / K / V^T ----------
__global__ __launch_bounds__(512, 1) void gemm_qkv(const ushort* __restrict__ A,
                                                   const ushort* __restrict__ Bt,
                                                   const ushort* __restrict__ bias,
                                                   ushort* __restrict__ Qb,
                                                   ushort* __restrict__ Kb,
                                                   ushort* __restrict__ Vtb) {
  GEMM_CORE(A, Bt, acc)
  #pragma unroll
  for (int ni = 0; ni < 4; ++ni) {
    const int n = n0 + wn * 64 + ni * 16 + col;  // 0..3071
    const float bi = bf2f(bias[n]);
    const int which = n >> 10;                   // 0=Q 1=K 2=V
    const int within = n & 1023;
    const int h = within >> 6, d = within & 63;
    if (which == 2) {
      // V^T: per (mi) the r=0..3 outputs are 4 consecutive t -> ushort4 store
      #pragma unroll
      for (int mi = 0; mi < 4; ++mi) {
        const int row0 = m0 + wm * 64 + mi * 16 + quad * 4;   // multiple of 4
        const int b = row0 >> 11, t0 = row0 & 2047;
        ushort4 y;
        y.x = f2bf(acc[mi][ni][0] + bi);
        y.y = f2bf(acc[mi][ni][1] + bi);
        y.z = f2bf(acc[mi][ni][2] + bi);
        y.w = f2bf(acc[mi][ni][3] + bi);
        *(ushort4*)(Vtb + ((size_t)(b * Hc + h) * Dc + d) * Tc + t0) = y;
      }
    } else {
      #pragma unroll
      for (int mi = 0; mi < 4; ++mi) {
        #pragma unroll
        for (int r = 0; r < 4; ++r) {
          const int row = m0 + wm * 64 + mi * 16 + quad * 4 + r;  // 0..8191
          const float v = acc[mi][ni][r] + bi;
          const int b = row >> 11, t = row & 2047;
          const size_t hb = (size_t)(b * Hc + h);
          const ushort ub = f2bf(v);
          if (which == 0) Qb[(hb * Tc + t) * Dc + d] = ub;
          else            Kb[(hb * Tc + t) * Dc + d] = ub;
        }
      }
    }
  }
}

// ---------- GEMM 2: out = y @ W_out + b_out ----------
__global__ __launch_bounds__(512, 1) void gemm_out(const ushort* __restrict__ A,
                                                   const ushort* __restrict__ Bt,
                                                   const ushort* __restrict__ bias,
                                                   void* __restrict__ out,
                                                   const int* __restrict__ flag) {
  GEMM_CORE(A, Bt, acc)
  const bool isbf = (*flag != 0);
  #pragma unroll
  for (int ni = 0; ni < 4; ++ni) {
    const int n = n0 + wn * 64 + ni * 16 + col;
    const float bi = bf2f(bias[n]);
    #pragma unroll
    for (int mi = 0; mi < 4; ++mi) {
      #pragma unroll
      for (int r = 0; r < 4; ++r) {
        const int row = m0 + wm * 64 + mi * 16 + quad * 4 + r;
        const float v = acc[mi][ni][r] + bi;
        const size_t idx = (size_t)row * 1024 + n;
        if (isbf) ((ushort*)out)[idx] = f2bf(v);
        else      ((float*)out)[idx] = v;
      }
    }
  }
}

// ---------- MFMA flash attention v8: XCD-affine bh, pair-balanced, 8w ------
// (round-7 verified; unchanged this round)
__global__ __launch_bounds__(512, 4) void attn_mfma(const ushort* __restrict__ Qb,
                                                    const ushort* __restrict__ Kb,
                                                    const ushort* __restrict__ Vtb,
                                                    ushort* __restrict__ Yb) {
  __shared__ __align__(16) ushort Kl[2][4096];   // [parity][64 rows * 64 swz]
  __shared__ __align__(16) ushort Vl[2][4096];   // 32 KB total
  const int tid = threadIdx.x;
  const int flat = blockIdx.x + (int)gridDim.x * blockIdx.y;  // x-major
  const int pair = flat >> 6;                  // 0..7
  const int bh = (flat & 7) * 8 + ((flat >> 3) & 7);  // 0..63, XCD-affine
  const int wave = tid >> 6, lane = tid & 63;
  const int col = lane & 15, quad = lane >> 4;
  const int pHI = 15 - pair;                 // 8..15
  const int pLO = pair;                      // 0..7
  const int nA = 2 * pHI + 2;                // chunks for HI panel (even)
  const int ntot = nA + 2 * pLO + 2;         // always 34

  const ushort* Qh = Qb + (size_t)bh * Tc * Dc;
  const ushort* Kh = Kb + (size_t)bh * Tc * Dc;
  const ushort* Vth = Vtb + (size_t)bh * Dc * Tc;

  // staging: slot s = tid holds global 16B-group (s&7)^((s>>3)&7) of row s>>3
  const int sr = tid >> 3, sg = (tid & 7) ^ (sr & 7);
  const ushort* kg = Kh + (size_t)sr * Dc + sg * 8;
  const ushort* vg = Vth + (size_t)sr * Tc + sg * 8;

  const int q0A = pHI * 128 + wave * 16;
  const int q0B = pLO * 128 + wave * 16;
  const int cdA = 2 * pHI + (wave >> 2);     // wave's diagonal chunk, phase A
  const int cdB = 2 * pLO + (wave >> 2);
  const int ktw = wave & 3;                  // diag sub-block within 64 keys

  // Q B-frags (16x16x32 B-operand: n=q=col, k=d=quad*8+j), both panels
  bf16x8 qfA[2], qfB[2];
  {
    const ushort* qa = Qh + (size_t)(q0A + col) * Dc + quad * 8;
    qfA[0] = *(const bf16x8*)(qa);
    qfA[1] = *(const bf16x8*)(qa + 32);
    const ushort* qb = Qh + (size_t)(q0B + col) * Dc + quad * 8;
    qfB[0] = *(const bf16x8*)(qb);
    qfB[1] = *(const bf16x8*)(qb + 32);
  }

  floatx4 o[4];       // [dt] O^T frags: row=d-local (quad*4+r), col=q
  float lpart = 0.f;
  #pragma unroll
  for (int dt = 0; dt < 4; ++dt) o[dt] = (floatx4){0.f, 0.f, 0.f, 0.f};

  constexpr float C1 = 0.18033688f;          //  0.125 * log2(e)
  constexpr float C2 = -17.312340f;          // -12    * log2(e)
  const int b = bh >> 4, h = bh & 15;

  auto stage = [&](int gi) {                 // gi = global chunk iteration
    const int p = gi & 1;
    const int c = (gi < nA) ? gi : gi - nA;  // key-chunk index within panel
    const size_t kOff = (size_t)c * 64;
#if HAVE_GLL
    async_load16(kg + kOff * Dc, &Kl[p][wave * 512]);
    async_load16(vg + kOff, &Vl[p][wave * 512]);
#else
    *(uint4*)&Kl[p][tid * 8] = *(const uint4*)(kg + kOff * Dc);
    *(uint4*)&Vl[p][tid * 8] = *(const uint4*)(vg + kOff);
#endif
  };

  auto chunk_compute = [&](int c, int p, const bf16x8 (&qf)[2], int cd) {
    if (c > cd) return;
    const bool masked = (c == cd);
    #pragma unroll
    for (int kt = 0; kt < 4; ++kt) {
      if (masked && kt > ktw) continue;      // fully-masked sub-block
      // K A-frags (m=kcol, k=d): row kt*16+col, groups quad / quad+4
      const int rowk = kt * 16 + col;
      const int swk = rowk & 7;
      bf16x8 ka0 = *(const bf16x8*)(&Kl[p][rowk * 64 + ((quad ^ swk) * 8)]);
      bf16x8 ka1 = *(const bf16x8*)(&Kl[p][rowk * 64 + (((quad + 4) ^ swk) * 8)]);
      // V^T A-frags for 16x16x16 (m=d, k=kpos=kt*16+quad*4+j): b64 reads
      bf16x4 vf[4];
      #pragma unroll
      for (int dt = 0; dt < 4; ++dt) {
        const int rowv = dt * 16 + col;
        const int gv = (2 * kt + (quad >> 1)) ^ (rowv & 7);
        vf[dt] = *(const bf16x4*)(&Vl[p][rowv * 64 + gv * 8 + (quad & 1) * 4]);
      }
      floatx4 sf = {0.f, 0.f, 0.f, 0.f};
      sf = __builtin_amdgcn_mfma_f32_16x16x32_bf16(ka0, qf[0], sf, 0, 0, 0);
      sf = __builtin_amdgcn_mfma_f32_16x16x32_bf16(ka1, qf[1], sf, 0, 0, 0);
      bf16x4 pb;
      float ps = 0.f;
      const bool tri = masked && (kt == ktw);
      #pragma unroll
      for (int r = 0; r < 4; ++r) {
        float pe = exp2_fast(fmaf(sf[r], C1, C2));
        if (tri) pe = (quad * 4 + r <= col) ? pe : 0.f;
        ps += pe;
        pb[r] = (__bf16)pe;                  // compiler pairs into cvt_pk
      }
      lpart += ps;
      #pragma unroll
      for (int dt = 0; dt < 4; ++dt)
        o[dt] = mfma16(vf[dt], pb, o[dt]);
    }
  };

  auto flush = [&](int q0) {
    float l = lpart;
    l += __shfl_xor(l, 16);
    l += __shfl_xor(l, 32);
    const float inv = 1.f / l;
    const int q = q0 + col;
    const size_t base = ((size_t)b * Tc + q) * Cdim + h * Dc;
    #pragma unroll
    for (int dt = 0; dt < 4; ++dt) {
      ushort4 y;
      y.x = f2bf(o[dt][0] * inv);
      y.y = f2bf(o[dt][1] * inv);
      y.z = f2bf(o[dt][2] * inv);
      y.w = f2bf(o[dt][3] * inv);
      *(ushort4*)(Yb + base + dt * 16 + quad * 4) = y;
    }
  };

  stage(0);
  __syncthreads();

  // ---- phase A: HI panel ----
  for (int c = 0; c < nA; ++c) {
    if (c + 1 < ntot) stage(c + 1);
    chunk_compute(c, c & 1, qfA, cdA);
    if (c == nA - 1) {
      flush(q0A);
      lpart = 0.f;
      #pragma unroll
      for (int dt = 0; dt < 4; ++dt) o[dt] = (floatx4){0.f, 0.f, 0.f, 0.f};
    }
    __syncthreads();   // drains stage(c+1) + protects parity reuse
  }
  // ---- phase B: LO panel ----
  for (int gi = nA; gi < ntot; ++gi) {
    if (gi + 1 < ntot) stage(gi + 1);
    chunk_compute(gi - nA, gi & 1, qfB, cdB);
    __syncthreads();
  }
  flush(q0B);
}

extern "C" void kernel_launch(void* const* d_in, const int* in_sizes, int n_in,
                              void* d_out, int out_size, void* d_ws, size_t ws_size,
                              hipStream_t stream) {
  const void* x    = d_in[0];
  const void* Wqkv = d_in[1];
  const void* bqkv = d_in[2];
  const void* Wout = d_in[3];
  const void* bout = d_in[4];

  char* ws = (char*)d_ws;
  size_t off = 0;
  auto alloc = [&](size_t bytes) { size_t r = off; off += (bytes + 255) & ~(size_t)255; return r; };

  int*    flag = (int*)   (ws + alloc(256));
  ushort* xb   = (ushort*)(ws + alloc((size_t)Mrows * Cdim * 2));      // also reused as Y
  ushort* wqt  = (ushort*)(ws + alloc((size_t)3 * Cdim * Cdim * 2));
  ushort* wot  = (ushort*)(ws + alloc((size_t)Cdim * Cdim * 2));
  ushort* bqb  = (ushort*)(ws + alloc((size_t)3 * Cdim * 2));
  ushort* bob  = (ushort*)(ws + alloc((size_t)Cdim * 2));
  ushort* Qb   = (ushort*)(ws + alloc((size_t)Mrows * Cdim * 2));
  ushort* Kb   = (ushort*)(ws + alloc((size_t)Mrows * Cdim * 2));
  ushort* Vtb  = (ushort*)(ws + alloc((size_t)Mrows * Cdim * 2));
  ushort* Yb   = xb;  // x is dead after gemm_qkv; reuse

  // 4 launches total (was 9): fused preprocess -> gemm_qkv -> attn -> gemm_out
  preprocess<<<12292, 256, 0, stream>>>(x, Wqkv, bqkv, Wout, bout,
                                        xb, wqt, bqb, wot, bob, flag);
  gemm_qkv<<<dim3(24, 32), 512, 0, stream>>>(xb, wqt, bqb, Qb, Kb, Vtb);
  attn_mfma<<<dim3(8, 64), 512, 0, stream>>>(Qb, Kb, Vtb, Yb);
  gemm_out<<<dim3(8, 32), 512, 0, stream>>>(Yb, wot, bob, d_out, flag);
}

// Round 10
// 256.085 us; speedup vs baseline: 1.0212x; 1.0212x over previous
//
#include <hip/hip_runtime.h>
#include <math.h>

typedef __bf16 bf16x8 __attribute__((ext_vector_type(8)));
typedef __bf16 bf16x4 __attribute__((ext_vector_type(4)));
typedef short shortx4 __attribute__((ext_vector_type(4)));
typedef float floatx4 __attribute__((ext_vector_type(4)));

#define Tc 2048
#define Cdim 1024
#define Hc 16
#define Dc 64
#define Mrows 8192

__device__ __forceinline__ float bf2f(ushort u) {
  union { float f; unsigned int i; } v; v.i = ((unsigned int)u) << 16; return v.f;
}
__device__ __forceinline__ ushort f2bf(float f) {
  union { float f; unsigned int i; } v; v.f = f;
  unsigned int r = (v.i + 0x7FFFu + ((v.i >> 16) & 1u)) >> 16;
  return (ushort)r;
}
__device__ __forceinline__ float exp2_fast(float x) {
#if __has_builtin(__builtin_amdgcn_exp2f)
  return __builtin_amdgcn_exp2f(x);
#else
  return exp2f(x);
#endif
}

// ---- 16x16x16 bf16 MFMA with compile-safe fallbacks (round-4 verified) ----
#if __has_builtin(__builtin_amdgcn_mfma_f32_16x16x16_bf16)
__device__ __forceinline__ floatx4 mfma16(bf16x4 a, bf16x4 b, floatx4 c) {
  return __builtin_amdgcn_mfma_f32_16x16x16_bf16(a, b, c, 0, 0, 0);
}
#elif __has_builtin(__builtin_amdgcn_mfma_f32_16x16x16bf16_1k)
__device__ __forceinline__ floatx4 mfma16(bf16x4 a, bf16x4 b, floatx4 c) {
  union { bf16x4 bv; shortx4 sv; } ua, ub;
  ua.bv = a; ub.bv = b;
  return __builtin_amdgcn_mfma_f32_16x16x16bf16_1k(ua.sv, ub.sv, c, 0, 0, 0);
}
#else
__device__ __forceinline__ floatx4 mfma16(bf16x4 a, bf16x4 b, floatx4 c) {
  floatx4 d;
  asm("v_mfma_f32_16x16x16_bf16 %0, %1, %2, %3" : "=v"(d) : "v"(a), "v"(b), "v"(c));
  return d;
}
#endif

#if __has_builtin(__builtin_amdgcn_global_load_lds)
#define HAVE_GLL 1
__device__ __forceinline__ void async_load16(const ushort* g, ushort* l) {
  __builtin_amdgcn_global_load_lds((const __attribute__((address_space(1))) void*)g,
                                   (__attribute__((address_space(3))) void*)l, 16, 0, 0);
}
#else
#define HAVE_GLL 0
#endif

// ---------- fused preprocess: sniff + convert x + transpose W's + biases ----
// (round-8 verified; unchanged)
__global__ __launch_bounds__(256) void preprocess(
    const void* __restrict__ x, const void* __restrict__ Wqkv,
    const void* __restrict__ bqkv, const void* __restrict__ Wout,
    const void* __restrict__ bout,
    ushort* __restrict__ xb, ushort* __restrict__ wqt, ushort* __restrict__ bqb,
    ushort* __restrict__ wot, ushort* __restrict__ bob, int* __restrict__ flag) {
  const int tid = threadIdx.x;
  __shared__ int cnt;
  __shared__ float tile[32][33];
  if (tid == 0) cnt = 0;
  __syncthreads();
  {
    const unsigned int* xw = (const unsigned int*)x;
    int local = 0;
    #pragma unroll
    for (int i = 0; i < 4; ++i) {
      unsigned int e = (xw[tid + i * 256] >> 7) & 0xFFu;
      if (e >= 100u && e <= 140u) local++;
    }
    atomicAdd(&cnt, local);
  }
  __syncthreads();
  const bool isbf = (cnt >= 614);
  const int bid = blockIdx.x;
  if (bid == 0 && tid == 0) *flag = isbf ? 1 : 0;

  if (bid < 8192) {                     // ---- convert x (4 elems/thread) ----
    const size_t i = (size_t)bid * 256 + tid;
    if (isbf) {
      ((ushort4*)xb)[i] = ((const ushort4*)x)[i];
    } else {
      float4 f = ((const float4*)x)[i];
      ushort4 y;
      y.x = f2bf(f.x); y.y = f2bf(f.y); y.z = f2bf(f.z); y.w = f2bf(f.w);
      ((ushort4*)xb)[i] = y;
    }
    return;
  }
  int t = bid - 8192;
  const int tx = tid & 31, ty = tid >> 5;
  if (t < 3072) {                       // ---- Wqkv^T: [1024][3072]->[3072][1024]
    const int bx = t % 96, by = t / 96;
    #pragma unroll
    for (int i = ty; i < 32; i += 8) {
      const int r = by * 32 + i, c = bx * 32 + tx;
      tile[i][tx] = isbf ? bf2f(((const ushort*)Wqkv)[(size_t)r * 3072 + c])
                         : ((const float*)Wqkv)[(size_t)r * 3072 + c];
    }
    __syncthreads();
    #pragma unroll
    for (int i = ty; i < 32; i += 8) {
      const int cc = bx * 32 + i, rr = by * 32 + tx;
      wqt[(size_t)cc * 1024 + rr] = f2bf(tile[tx][i]);
    }
    return;
  }
  t -= 3072;
  if (t < 1024) {                       // ---- Wout^T: [1024][1024]->[1024][1024]
    const int bx = t & 31, by = t >> 5;
    #pragma unroll
    for (int i = ty; i < 32; i += 8) {
      const int r = by * 32 + i, c = bx * 32 + tx;
      tile[i][tx] = isbf ? bf2f(((const ushort*)Wout)[(size_t)r * 1024 + c])
                         : ((const float*)Wout)[(size_t)r * 1024 + c];
    }
    __syncthreads();
    #pragma unroll
    for (int i = ty; i < 32; i += 8) {
      const int cc = bx * 32 + i, rr = by * 32 + tx;
      wot[(size_t)cc * 1024 + rr] = f2bf(tile[tx][i]);
    }
    return;
  }
  t -= 1024;
  if (t < 3) {                          // ---- bqkv (3 blocks x 1024 elems) ----
    const int i = t * 256 + tid;
    if (isbf) {
      ((ushort4*)bqb)[i] = ((const ushort4*)bqkv)[i];
    } else {
      float4 f = ((const float4*)bqkv)[i];
      ushort4 y;
      y.x = f2bf(f.x); y.y = f2bf(f.y); y.z = f2bf(f.z); y.w = f2bf(f.w);
      ((ushort4*)bqb)[i] = y;
    }
    return;
  }
  {                                     // ---- bout (1 block x 1024 elems) ----
    const int i = tid;
    if (isbf) {
      ((ushort4*)bob)[i] = ((const ushort4*)bout)[i];
    } else {
      float4 f = ((const float4*)bout)[i];
      ushort4 y;
      y.x = f2bf(f.x); y.y = f2bf(f.y); y.z = f2bf(f.z); y.w = f2bf(f.w);
      ((ushort4*)bob)[i] = y;
    }
  }
}

// ===== 256x128 GEMM core: counted-vmcnt pipelined dbuf (BK=64, dist-2) =====
// Schedule = round-6/7/8 verified (4 consecutive passing runs) — UNCHANGED.
// New this round: XCD-affine block remap (pure index permutation, zero
// sync-structure risk). x-major flat%8 = XCD (empirically validated by the
// round-7 attn fix): XCD k owns a contiguous band of gridDim.y/8 = 4 A-row
// panels (4 x 512KB = 2MB, L2-resident) and sweeps all B columns through it.
// Old mapping sprayed the 24 readers of each A panel across all 8 XCDs ->
// 57 MB of A re-fetch (FETCH 79 MB vs 22 MB unique inputs).
// Bijection: flat in [0,768) [or 256]; k=flat&7; j=flat>>3 in [0,96) [32];
// by = k*4 + j/gx in [4k,4k+4); bx = j%gx. Both grids: gy=32, total%8==0.
#if HAVE_GLL

#define GEMM_CORE(A_, Bt_, acc_)                                               \
  __shared__ __align__(16) ushort As[2][256 * 64];                             \
  __shared__ __align__(16) ushort Bs[2][128 * 64];                             \
  const int tid = threadIdx.x;                                                 \
  const int wave = tid >> 6, lane = tid & 63;                                  \
  const int col = lane & 15, quad = lane >> 4;                                 \
  const int wm = wave >> 1, wn = wave & 1;                                     \
  const int flatw = blockIdx.x + (int)gridDim.x * blockIdx.y;                  \
  const int xcd_ = flatw & 7, jj_ = flatw >> 3;                                \
  const int ypx_ = (int)gridDim.y >> 3;                                        \
  const int by_ = xcd_ * ypx_ + jj_ / (int)gridDim.x;                          \
  const int bx_ = jj_ % (int)gridDim.x;                                        \
  const int m0 = by_ * 256, n0 = bx_ * 128;                                    \
  const int rl0 = tid >> 3, gsw = (tid & 7) ^ (rl0 & 7);                       \
  floatx4 acc_[4][4];                                                          \
  _Pragma("unroll") for (int i = 0; i < 4; ++i)                                \
    _Pragma("unroll") for (int j = 0; j < 4; ++j)                              \
      acc_[i][j] = (floatx4){0.f, 0.f, 0.f, 0.f};                              \
  auto stage_ = [&](int u) {                                                   \
    const int bb = u & 1;                                                      \
    _Pragma("unroll") for (int h = 0; h < 2; ++h)                              \
      _Pragma("unroll") for (int i = 0; i < 2; ++i) {                          \
        const int rl = i * 64 + rl0;                                           \
        async_load16(A_ + (size_t)(m0 + h * 128 + rl) * 1024 + u * 64 + gsw * 8, \
                     &As[bb][(h * 1024 + i * 512 + wave * 64) * 8]);           \
      }                                                                        \
    _Pragma("unroll") for (int i = 0; i < 2; ++i) {                            \
      const int rl = i * 64 + rl0;                                             \
      async_load16(Bt_ + (size_t)(n0 + rl) * 1024 + u * 64 + gsw * 8,          \
                   &Bs[bb][(i * 512 + wave * 64) * 8]);                        \
    }                                                                          \
  };                                                                           \
  stage_(0);                                                                   \
  stage_(1);                                                                   \
  asm volatile("s_waitcnt vmcnt(6)" ::: "memory");                             \
  __builtin_amdgcn_sched_barrier(0);                                           \
  __builtin_amdgcn_s_barrier();                                                \
  for (int t = 0; t < 16; ++t) {                                               \
    const ushort* Ab = As[t & 1];                                              \
    const ushort* Bb = Bs[t & 1];                                              \
    bf16x8 af[2][4], bfv[2][4];                                                \
    _Pragma("unroll") for (int ks = 0; ks < 2; ++ks) {                         \
      _Pragma("unroll") for (int mi = 0; mi < 4; ++mi) {                       \
        const int rr = wm * 64 + mi * 16 + col;                                \
        const int gg = (ks * 4 + quad) ^ (rr & 7);                             \
        af[ks][mi] = *(const bf16x8*)(Ab + rr * 64 + gg * 8);                  \
      }                                                                        \
      _Pragma("unroll") for (int ni = 0; ni < 4; ++ni) {                       \
        const int rr = wn * 64 + ni * 16 + col;                                \
        const int gg = (ks * 4 + quad) ^ (rr & 7);                             \
        bfv[ks][ni] = *(const bf16x8*)(Bb + rr * 64 + gg * 8);                 \
      }                                                                        \
    }                                                                          \
    asm volatile("s_waitcnt lgkmcnt(0)" ::: "memory");                         \
    __builtin_amdgcn_sched_barrier(0);                                         \
    __builtin_amdgcn_s_barrier();                                              \
    if (t + 2 < 16) stage_(t + 2);                                             \
    __builtin_amdgcn_s_setprio(1);                                             \
    _Pragma("unroll") for (int mi = 0; mi < 4; ++mi)                           \
      _Pragma("unroll") for (int ni = 0; ni < 4; ++ni) {                       \
        acc_[mi][ni] = __builtin_amdgcn_mfma_f32_16x16x32_bf16(                \
            af[0][mi], bfv[0][ni], acc_[mi][ni], 0, 0, 0);                     \
        acc_[mi][ni] = __builtin_amdgcn_mfma_f32_16x16x32_bf16(                \
            af[1][mi], bfv[1][ni], acc_[mi][ni], 0, 0, 0);                     \
      }                                                                        \
    __builtin_amdgcn_s_setprio(0);                                             \
    if (t + 2 < 16) { asm volatile("s_waitcnt vmcnt(6)" ::: "memory"); }       \
    else            { asm volatile("s_waitcnt vmcnt(0)" ::: "memory"); }       \
    __builtin_amdgcn_sched_barrier(0);                                         \
    __builtin_amdgcn_s_barrier();                                              \
  }

#else  // !HAVE_GLL: synchronous dbuf fallback, same geometry (compile safety)

#define GEMM_CORE(A_, Bt_, acc_)                                               \
  __shared__ __align__(16) ushort As[2][256 * 64];                             \
  __shared__ __align__(16) ushort Bs[2][128 * 64];                             \
  const int tid = threadIdx.x;                                                 \
  const int wave = tid >> 6, lane = tid & 63;                                  \
  const int col = lane & 15, quad = lane >> 4;                                 \
  const int wm = wave >> 1, wn = wave & 1;                                     \
  const int flatw = blockIdx.x + (int)gridDim.x * blockIdx.y;                  \
  const int xcd_ = flatw & 7, jj_ = flatw >> 3;                                \
  const int ypx_ = (int)gridDim.y >> 3;                                        \
  const int by_ = xcd_ * ypx_ + jj_ / (int)gridDim.x;                          \
  const int bx_ = jj_ % (int)gridDim.x;                                        \
  const int m0 = by_ * 256, n0 = bx_ * 128;                                    \
  const int rl0 = tid >> 3, gsw = (tid & 7) ^ (rl0 & 7);                       \
  floatx4 acc_[4][4];                                                          \
  _Pragma("unroll") for (int i = 0; i < 4; ++i)                                \
    _Pragma("unroll") for (int j = 0; j < 4; ++j)                              \
      acc_[i][j] = (floatx4){0.f, 0.f, 0.f, 0.f};                              \
  auto stage_ = [&](int u) {                                                   \
    const int bb = u & 1;                                                      \
    _Pragma("unroll") for (int h = 0; h < 2; ++h)                              \
      _Pragma("unroll") for (int i = 0; i < 2; ++i) {                          \
        const int rl = i * 64 + rl0;                                           \
        *(uint4*)&As[bb][(h * 1024 + i * 512 + wave * 64 + lane) * 8] =        \
            *(const uint4*)(A_ + (size_t)(m0 + h * 128 + rl) * 1024 + u * 64 + gsw * 8); \
      }                                                                        \
    _Pragma("unroll") for (int i = 0; i < 2; ++i) {                            \
      const int rl = i * 64 + rl0;                                             \
      *(uint4*)&Bs[bb][(i * 512 + wave * 64 + lane) * 8] =                     \
          *(const uint4*)(Bt_ + (size_t)(n0 + rl) * 1024 + u * 64 + gsw * 8);  \
    }                                                                          \
  };                                                                           \
  stage_(0);                                                                   \
  __syncthreads();                                                             \
  for (int t = 0; t < 16; ++t) {                                               \
    if (t + 1 < 16) stage_(t + 1);                                             \
    const ushort* Ab = As[t & 1];                                              \
    const ushort* Bb = Bs[t & 1];                                              \
    _Pragma("unroll") for (int ks = 0; ks < 2; ++ks) {                         \
      bf16x8 af[4], bfv[4];                                                    \
      _Pragma("unroll") for (int mi = 0; mi < 4; ++mi) {                       \
        const int rr = wm * 64 + mi * 16 + col;                                \
        const int gg = (ks * 4 + quad) ^ (rr & 7);                             \
        af[mi] = *(const bf16x8*)(Ab + rr * 64 + gg * 8);                      \
      }                                                                        \
      _Pragma("unroll") for (int ni = 0; ni < 4; ++ni) {                       \
        const int rr = wn * 64 + ni * 16 + col;                                \
        const int gg = (ks * 4 + quad) ^ (rr & 7);                             \
        bfv[ni] = *(const bf16x8*)(Bb + rr * 64 + gg * 8);                     \
      }                                                                        \
      _Pragma("unroll") for (int mi = 0; mi < 4; ++mi)                         \
        _Pragma("unroll") for (int ni = 0; ni < 4; ++ni)                       \
          acc_[mi][ni] = __builtin_amdgcn_mfma_f32_16x16x32_bf16(              \
              af[mi], bfv[ni], acc_[mi][ni], 0, 0, 0);                         \
    }                                                                          \
    __syncthreads();                                                           \
  }

#endif  // HAVE_GLL

// ---------- GEMM 1: qkv = x @ W_qkv + b, scatter into Q / K / V^T ----------
__global__ __launch_bounds__(512, 1) void gemm_qkv(const ushort* __restrict__ A,
                                                   const ushort* __restrict__ Bt,
                                                   const ushort* __restrict__ bias,
                                                   ushort* __restrict__ Qb,
                                                   ushort* __restrict__ Kb,
                                                   ushort* __restrict__ Vtb) {
  GEMM_CORE(A, Bt, acc)
  #pragma unroll
  for (int ni = 0; ni < 4; ++ni) {
    const int n = n0 + wn * 64 + ni * 16 + col;  // 0..3071
    const float bi = bf2f(bias[n]);
    const int which = n >> 10;                   // 0=Q 1=K 2=V
    const int within = n & 1023;
    const int h = within >> 6, d = within & 63;
    if (which == 2) {
      // V^T: per (mi) the r=0..3 outputs are 4 consecutive t -> ushort4 store
      #pragma unroll
      for (int mi = 0; mi < 4; ++mi) {
        const int row0 = m0 + wm * 64 + mi * 16 + quad * 4;   // multiple of 4
        const int b = row0 >> 11, t0 = row0 & 2047;
        ushort4 y;
        y.x = f2bf(acc[mi][ni][0] + bi);
        y.y = f2bf(acc[mi][ni][1] + bi);
        y.z = f2bf(acc[mi][ni][2] + bi);
        y.w = f2bf(acc[mi][ni][3] + bi);
        *(ushort4*)(Vtb + ((size_t)(b * Hc + h) * Dc + d) * Tc + t0) = y;
      }
    } else {
      #pragma unroll
      for (int mi = 0; mi < 4; ++mi) {
        #pragma unroll
        for (int r = 0; r < 4; ++r) {
          const int row = m0 + wm * 64 + mi * 16 + quad * 4 + r;  // 0..8191
          const float v = acc[mi][ni][r] + bi;
          const int b = row >> 11, t = row & 2047;
          const size_t hb = (size_t)(b * Hc + h);
          const ushort ub = f2bf(v);
          if (which == 0) Qb[(hb * Tc + t) * Dc + d] = ub;
          else            Kb[(hb * Tc + t) * Dc + d] = ub;
        }
      }
    }
  }
}

// ---------- GEMM 2: out = y @ W_out + b_out ----------
__global__ __launch_bounds__(512, 1) void gemm_out(const ushort* __restrict__ A,
                                                   const ushort* __restrict__ Bt,
                                                   const ushort* __restrict__ bias,
                                                   void* __restrict__ out,
                                                   const int* __restrict__ flag) {
  GEMM_CORE(A, Bt, acc)
  const bool isbf = (*flag != 0);
  #pragma unroll
  for (int ni = 0; ni < 4; ++ni) {
    const int n = n0 + wn * 64 + ni * 16 + col;
    const float bi = bf2f(bias[n]);
    #pragma unroll
    for (int mi = 0; mi < 4; ++mi) {
      #pragma unroll
      for (int r = 0; r < 4; ++r) {
        const int row = m0 + wm * 64 + mi * 16 + quad * 4 + r;
        const float v = acc[mi][ni][r] + bi;
        const size_t idx = (size_t)row * 1024 + n;
        if (isbf) ((ushort*)out)[idx] = f2bf(v);
        else      ((float*)out)[idx] = v;
      }
    }
  }
}

// ---------- MFMA flash attention v8: XCD-affine bh, pair-balanced, 8w ------
// (round-7 verified; unchanged this round)
__global__ __launch_bounds__(512, 4) void attn_mfma(const ushort* __restrict__ Qb,
                                                    const ushort* __restrict__ Kb,
                                                    const ushort* __restrict__ Vtb,
                                                    ushort* __restrict__ Yb) {
  __shared__ __align__(16) ushort Kl[2][4096];   // [parity][64 rows * 64 swz]
  __shared__ __align__(16) ushort Vl[2][4096];   // 32 KB total
  const int tid = threadIdx.x;
  const int flat = blockIdx.x + (int)gridDim.x * blockIdx.y;  // x-major
  const int pair = flat >> 6;                  // 0..7
  const int bh = (flat & 7) * 8 + ((flat >> 3) & 7);  // 0..63, XCD-affine
  const int wave = tid >> 6, lane = tid & 63;
  const int col = lane & 15, quad = lane >> 4;
  const int pHI = 15 - pair;                 // 8..15
  const int pLO = pair;                      // 0..7
  const int nA = 2 * pHI + 2;                // chunks for HI panel (even)
  const int ntot = nA + 2 * pLO + 2;         // always 34

  const ushort* Qh = Qb + (size_t)bh * Tc * Dc;
  const ushort* Kh = Kb + (size_t)bh * Tc * Dc;
  const ushort* Vth = Vtb + (size_t)bh * Dc * Tc;

  // staging: slot s = tid holds global 16B-group (s&7)^((s>>3)&7) of row s>>3
  const int sr = tid >> 3, sg = (tid & 7) ^ (sr & 7);
  const ushort* kg = Kh + (size_t)sr * Dc + sg * 8;
  const ushort* vg = Vth + (size_t)sr * Tc + sg * 8;

  const int q0A = pHI * 128 + wave * 16;
  const int q0B = pLO * 128 + wave * 16;
  const int cdA = 2 * pHI + (wave >> 2);     // wave's diagonal chunk, phase A
  const int cdB = 2 * pLO + (wave >> 2);
  const int ktw = wave & 3;                  // diag sub-block within 64 keys

  // Q B-frags (16x16x32 B-operand: n=q=col, k=d=quad*8+j), both panels
  bf16x8 qfA[2], qfB[2];
  {
    const ushort* qa = Qh + (size_t)(q0A + col) * Dc + quad * 8;
    qfA[0] = *(const bf16x8*)(qa);
    qfA[1] = *(const bf16x8*)(qa + 32);
    const ushort* qb = Qh + (size_t)(q0B + col) * Dc + quad * 8;
    qfB[0] = *(const bf16x8*)(qb);
    qfB[1] = *(const bf16x8*)(qb + 32);
  }

  floatx4 o[4];       // [dt] O^T frags: row=d-local (quad*4+r), col=q
  float lpart = 0.f;
  #pragma unroll
  for (int dt = 0; dt < 4; ++dt) o[dt] = (floatx4){0.f, 0.f, 0.f, 0.f};

  constexpr float C1 = 0.18033688f;          //  0.125 * log2(e)
  constexpr float C2 = -17.312340f;          // -12    * log2(e)
  const int b = bh >> 4, h = bh & 15;

  auto stage = [&](int gi) {                 // gi = global chunk iteration
    const int p = gi & 1;
    const int c = (gi < nA) ? gi : gi - nA;  // key-chunk index within panel
    const size_t kOff = (size_t)c * 64;
#if HAVE_GLL
    async_load16(kg + kOff * Dc, &Kl[p][wave * 512]);
    async_load16(vg + kOff, &Vl[p][wave * 512]);
#else
    *(uint4*)&Kl[p][tid * 8] = *(const uint4*)(kg + kOff * Dc);
    *(uint4*)&Vl[p][tid * 8] = *(const uint4*)(vg + kOff);
#endif
  };

  auto chunk_compute = [&](int c, int p, const bf16x8 (&qf)[2], int cd) {
    if (c > cd) return;
    const bool masked = (c == cd);
    #pragma unroll
    for (int kt = 0; kt < 4; ++kt) {
      if (masked && kt > ktw) continue;      // fully-masked sub-block
      // K A-frags (m=kcol, k=d): row kt*16+col, groups quad / quad+4
      const int rowk = kt * 16 + col;
      const int swk = rowk & 7;
      bf16x8 ka0 = *(const bf16x8*)(&Kl[p][rowk * 64 + ((quad ^ swk) * 8)]);
      bf16x8 ka1 = *(const bf16x8*)(&Kl[p][rowk * 64 + (((quad + 4) ^ swk) * 8)]);
      // V^T A-frags for 16x16x16 (m=d, k=kpos=kt*16+quad*4+j): b64 reads
      bf16x4 vf[4];
      #pragma unroll
      for (int dt = 0; dt < 4; ++dt) {
        const int rowv = dt * 16 + col;
        const int gv = (2 * kt + (quad >> 1)) ^ (rowv & 7);
        vf[dt] = *(const bf16x4*)(&Vl[p][rowv * 64 + gv * 8 + (quad & 1) * 4]);
      }
      floatx4 sf = {0.f, 0.f, 0.f, 0.f};
      sf = __builtin_amdgcn_mfma_f32_16x16x32_bf16(ka0, qf[0], sf, 0, 0, 0);
      sf = __builtin_amdgcn_mfma_f32_16x16x32_bf16(ka1, qf[1], sf, 0, 0, 0);
      bf16x4 pb;
      float ps = 0.f;
      const bool tri = masked && (kt == ktw);
      #pragma unroll
      for (int r = 0; r < 4; ++r) {
        float pe = exp2_fast(fmaf(sf[r], C1, C2));
        if (tri) pe = (quad * 4 + r <= col) ? pe : 0.f;
        ps += pe;
        pb[r] = (__bf16)pe;                  // compiler pairs into cvt_pk
      }
      lpart += ps;
      #pragma unroll
      for (int dt = 0; dt < 4; ++dt)
        o[dt] = mfma16(vf[dt], pb, o[dt]);
    }
  };

  auto flush = [&](int q0) {
    float l = lpart;
    l += __shfl_xor(l, 16);
    l += __shfl_xor(l, 32);
    const float inv = 1.f / l;
    const int q = q0 + col;
    const size_t base = ((size_t)b * Tc + q) * Cdim + h * Dc;
    #pragma unroll
    for (int dt = 0; dt < 4; ++dt) {
      ushort4 y;
      y.x = f2bf(o[dt][0] * inv);
      y.y = f2bf(o[dt][1] * inv);
      y.z = f2bf(o[dt][2] * inv);
      y.w = f2bf(o[dt][3] * inv);
      *(ushort4*)(Yb + base + dt * 16 + quad * 4) = y;
    }
  };

  stage(0);
  __syncthreads();

  // ---- phase A: HI panel ----
  for (int c = 0; c < nA; ++c) {
    if (c + 1 < ntot) stage(c + 1);
    chunk_compute(c, c & 1, qfA, cdA);
    if (c == nA - 1) {
      flush(q0A);
      lpart = 0.f;
      #pragma unroll
      for (int dt = 0; dt < 4; ++dt) o[dt] = (floatx4){0.f, 0.f, 0.f, 0.f};
    }
    __syncthreads();   // drains stage(c+1) + protects parity reuse
  }
  // ---- phase B: LO panel ----
  for (int gi = nA; gi < ntot; ++gi) {
    if (gi + 1 < ntot) stage(gi + 1);
    chunk_compute(gi - nA, gi & 1, qfB, cdB);
    __syncthreads();
  }
  flush(q0B);
}

extern "C" void kernel_launch(void* const* d_in, const int* in_sizes, int n_in,
                              void* d_out, int out_size, void* d_ws, size_t ws_size,
                              hipStream_t stream) {
  const void* x    = d_in[0];
  const void* Wqkv = d_in[1];
  const void* bqkv = d_in[2];
  const void* Wout = d_in[3];
  const void* bout = d_in[4];

  char* ws = (char*)d_ws;
  size_t off = 0;
  auto alloc = [&](size_t bytes) { size_t r = off; off += (bytes + 255) & ~(size_t)255; return r; };

  int*    flag = (int*)   (ws + alloc(256));
  ushort* xb   = (ushort*)(ws + alloc((size_t)Mrows * Cdim * 2));      // also reused as Y
  ushort* wqt  = (ushort*)(ws + alloc((size_t)3 * Cdim * Cdim * 2));
  ushort* wot  = (ushort*)(ws + alloc((size_t)Cdim * Cdim * 2));
  ushort* bqb  = (ushort*)(ws + alloc((size_t)3 * Cdim * 2));
  ushort* bob  = (ushort*)(ws + alloc((size_t)Cdim * 2));
  ushort* Qb   = (ushort*)(ws + alloc((size_t)Mrows * Cdim * 2));
  ushort* Kb   = (ushort*)(ws + alloc((size_t)Mrows * Cdim * 2));
  ushort* Vtb  = (ushort*)(ws + alloc((size_t)Mrows * Cdim * 2));
  ushort* Yb   = xb;  // x is dead after gemm_qkv; reuse

  // 4 launches: fused preprocess -> gemm_qkv -> attn -> gemm_out
  preprocess<<<12292, 256, 0, stream>>>(x, Wqkv, bqkv, Wout, bout,
                                        xb, wqt, bqb, wot, bob, flag);
  gemm_qkv<<<dim3(24, 32), 512, 0, stream>>>(xb, wqt, bqb, Qb, Kb, Vtb);
  attn_mfma<<<dim3(8, 64), 512, 0, stream>>>(Qb, Kb, Vtb, Yb);
  gemm_out<<<dim3(8, 32), 512, 0, stream>>>(Yb, wot, bob, d_out, flag);
}